// Round 6
// baseline (450.443 us; speedup 1.0000x reference)
//
#include <hip/hip_runtime.h>

typedef __bf16 bf16x8 __attribute__((ext_vector_type(8)));
typedef __bf16 bf16x4 __attribute__((ext_vector_type(4)));
typedef float f32x4 __attribute__((ext_vector_type(4)));

__device__ __forceinline__ float bf2f(unsigned short u) {
  union { unsigned int i; float f; } v; v.i = ((unsigned int)u) << 16; return v.f;
}
__device__ __forceinline__ unsigned short f2bf(float f) {
  union { float f; unsigned int i; } v; v.f = f;
  unsigned int u = v.i;
  u += 0x7fffu + ((u >> 16) & 1u);
  return (unsigned short)(u >> 16);
}

// ---------------- fused convert: x (dual), flat weights, transposed who/wvo
__global__ void cvt_all(const float* __restrict__ x,
                        const float* __restrict__ wv, const float* __restrict__ wh,
                        const float* __restrict__ w1, const float* __restrict__ w2,
                        const float* __restrict__ who, const float* __restrict__ wvo,
                        unsigned short* __restrict__ xb, unsigned short* __restrict__ xt,
                        unsigned short* __restrict__ wvb, unsigned short* __restrict__ whb,
                        unsigned short* __restrict__ w1b, unsigned short* __restrict__ w2b,
                        unsigned short* __restrict__ whoT, unsigned short* __restrict__ wvoT)
{
  const int bid = blockIdx.x;
  const int t = threadIdx.x;
  if (bid < 18432) {
    const int ro = bid * 2 + (t >> 7);           // xt row = s*192+b
    const int idx = t & 127;
    const int s = ro / 192, b = ro - s * 192;
    const int ri = b * 192 + s;                  // x/xb row
    float4 v = *(const float4*)&x[(size_t)ri * 512 + idx * 4];
    ushort4 o;
    o.x = f2bf(v.x); o.y = f2bf(v.y); o.z = f2bf(v.z); o.w = f2bf(v.w);
    *(ushort4*)&xb[(size_t)ri * 512 + idx * 4] = o;
    *(ushort4*)&xt[(size_t)ro * 512 + idx * 4] = o;
  } else if (bid < 20736) {
    int q = (bid - 18432) * 256 + t;
    const float* src; unsigned short* dst;
    if (q < 196608)      { src = wv;  dst = wvb; }
    else if (q < 393216) { src = wh;  dst = whb; q -= 196608; }
    else if (q < 524288) { src = w1;  dst = w1b; q -= 393216; }
    else                 { src = w2;  dst = w2b; q -= 524288; }
    float4 v = ((const float4*)src)[q];
    ushort4 o;
    o.x = f2bf(v.x); o.y = f2bf(v.y); o.z = f2bf(v.z); o.w = f2bf(v.w);
    ((ushort4*)dst)[q] = o;
  } else {
    const int tb = bid - 20736;
    const float* src = (tb < 256) ? who : wvo;
    unsigned short* dst = (tb < 256) ? whoT : wvoT;
    const int j = (tb & 255) * 2 + (t >> 7);
    const int i0 = (t & 127) * 4;
    ushort4 o;
    o.x = f2bf(src[(size_t)(i0 + 0) * 512 + j]);
    o.y = f2bf(src[(size_t)(i0 + 1) * 512 + j]);
    o.z = f2bf(src[(size_t)(i0 + 2) * 512 + j]);
    o.w = f2bf(src[(size_t)(i0 + 3) * 512 + j]);
    *(ushort4*)&dst[(size_t)j * 512 + i0] = o;
  }
}

// ---------------- fused MLP1 bias: bf = b1 + W1a.h_out_b + W1b.v_out_b ----
__global__ void fuse_bias(const float* __restrict__ b1,
                          const float* __restrict__ hob,
                          const float* __restrict__ vob,
                          const float* __restrict__ w1,
                          float* __restrict__ bf)
{
  const int gid = blockIdx.x * 256 + threadIdx.x;
  const int o = gid >> 4, g = gid & 15;
  if (o < 512) {
    const float* row = w1 + (size_t)o * 1024;
    float s = 0.f;
    #pragma unroll 8
    for (int m = g * 32; m < g * 32 + 32; ++m) s += row[m] * hob[m];
    #pragma unroll 8
    for (int m = g * 32; m < g * 32 + 32; ++m) s += row[512 + m] * vob[m];
    s += __shfl_xor(s, 1);
    s += __shfl_xor(s, 2);
    s += __shfl_xor(s, 4);
    s += __shfl_xor(s, 8);
    if (g == 0) bf[o] = s + b1[o];
  }
}

// ---------------- async global->LDS 16B ----------------
__device__ __forceinline__ void async16(const void* g, void* s) {
  __builtin_amdgcn_global_load_lds(
      (const __attribute__((address_space(1))) unsigned int*)g,
      (__attribute__((address_space(3))) unsigned int*)s, 16, 0, 0);
}

// ---------------- bf16 GEMM, Bt = (N,K) row-major (C = A * Bt^T) ----------
// 128x128 tile, BK=32, 4 waves (2x2), 16x16x32 MFMA.
// 3-buffer LDS pipeline, prefetch distance 2, counted vmcnt.
// T2 LDS XOR-swizzle (both-sides): tile row r holds global 16B-chunk
// (c ^ f(r)) at chunk-slot c, f(r) = (r>>1)&3. global_load_lds dest stays
// linear; the per-lane GLOBAL source col is pre-swizzled; ds_read col is
// XORed the same way. Kills the 8-lanes-per-bank conflict of 64B rows.
// MODE 0: C[M][ldC] at colOff. MODE 1: batched V^T (grid=batches*8,
//   tm=sub&3 over M=512, tn=sub>>2 covers cols tn*64..+127 of N=192;
//   middle 64 written twice, identical values). Bias by ROW in MODE 1.
template<int OUTF32, int RELU, int MODE, int ADDB>
__global__ __launch_bounds__(256, 3)
void gemm_bt(const unsigned short* __restrict__ A,
             const unsigned short* __restrict__ Bt,
             void* __restrict__ Cv,
             const float* __restrict__ bias,
             int M, int N, int K, int lda, int ldb, int ldC, int colOff)
{
  __shared__ unsigned short As[3][4096];
  __shared__ unsigned short Bs[3][4096];

  int tm, tn, batch = 0;
  if (MODE == 1) {
    batch = blockIdx.x >> 3;
    const int sub = blockIdx.x & 7;
    tm = sub & 3;
    tn = sub >> 2;
  } else {
    const int mb = M >> 7;
    tm = (int)blockIdx.x % mb;
    tn = (int)blockIdx.x / mb;
  }
  const int t = threadIdx.x;
  const int w = t >> 6, l = t & 63;
  const int wr = w >> 1, wc = w & 1;
  const int lr = l & 15, kg = l >> 4;

  const unsigned short* Abase = A + (size_t)tm * 128 * lda;
  const unsigned short* Bbase = (MODE == 1)
      ? Bt + ((size_t)batch * 192 + tn * 64) * ldb
      : Bt + (size_t)tn * 128 * ldb;

  // staging: lane fetches global row r0 (= its linear LDS row), but the
  // 16B chunk column is inverse-swizzled: c_src = (t&3) ^ f(r0),
  // f(r) = (r>>1)&3 = (t>>3)&3 here (w*8 is 0 mod 4).
  const int r0 = t >> 2;
  const int s0 = (((t & 3) ^ ((t >> 3) & 3))) * 8;
  const size_t ga0 = (size_t)r0 * lda + s0;
  const size_t ga1 = (size_t)(64 + r0) * lda + s0;
  const size_t gb0 = (size_t)r0 * ldb + s0;
  const size_t gb1 = (size_t)(64 + r0) * ldb + s0;
  const int ldsoff = w * 512;

  const f32x4 zero4 = {0.f, 0.f, 0.f, 0.f};
  f32x4 acc[4][4];
  #pragma unroll
  for (int m = 0; m < 4; ++m)
    #pragma unroll
    for (int n = 0; n < 4; ++n) acc[m][n] = zero4;

  auto stage = [&](int kt, int slot) {
    async16(Abase + ga0 + kt, &As[slot][ldsoff]);
    async16(Abase + ga1 + kt, &As[slot][2048 + ldsoff]);
    async16(Bbase + gb0 + kt, &Bs[slot][ldsoff]);
    async16(Bbase + gb1 + kt, &Bs[slot][2048 + ldsoff]);
  };

  const int nk = K >> 5;
  stage(0, 0);
  stage(32, 1);

  // read-side swizzle: row = wr*64 + m*16 + lr -> f(row) = (lr>>1)&3
  const int rsw = (kg ^ ((lr >> 1) & 3)) * 8;

  int cur = 0;
  for (int it = 0; it < nk; ++it) {
    int st = cur + 2; if (st >= 3) st -= 3;
    if (it + 2 < nk) {
      stage((it + 2) << 5, st);
      asm volatile("s_waitcnt vmcnt(8)" ::: "memory");   // tile it done; 8 in flight
    } else if (it + 1 < nk) {
      asm volatile("s_waitcnt vmcnt(4)" ::: "memory");
    } else {
      asm volatile("s_waitcnt vmcnt(0)" ::: "memory");
    }
    __builtin_amdgcn_sched_barrier(0);
    __builtin_amdgcn_s_barrier();          // all waves: tile it resident
    __builtin_amdgcn_sched_barrier(0);

    bf16x8 af[4], bfv[4];
    #pragma unroll
    for (int m = 0; m < 4; ++m)
      af[m] = *(const bf16x8*)&As[cur][(wr * 64 + m * 16 + lr) * 32 + rsw];
    #pragma unroll
    for (int n = 0; n < 4; ++n)
      bfv[n] = *(const bf16x8*)&Bs[cur][(wc * 64 + n * 16 + lr) * 32 + rsw];
    #pragma unroll
    for (int m = 0; m < 4; ++m)
      #pragma unroll
      for (int n = 0; n < 4; ++n)
        acc[m][n] = __builtin_amdgcn_mfma_f32_16x16x32_bf16(af[m], bfv[n],
                                                            acc[m][n], 0, 0, 0);
    __builtin_amdgcn_sched_barrier(0);
    __builtin_amdgcn_s_barrier();          // reads of slot cur done -> reusable
    cur = cur + 1; if (cur >= 3) cur = 0;
  }

  const int row0 = tm * 128 + wr * 64;
  const int colL0 = (MODE == 1) ? (tn * 64 + wc * 64) : (tn * 128 + wc * 64);

  if (MODE == 1) {
    unsigned short* Cw = (unsigned short*)Cv + (size_t)batch * 98304;
    #pragma unroll
    for (int m = 0; m < 4; ++m) {
      const int rowb = row0 + m * 16 + kg * 4;
      float4 bv4 = {0.f, 0.f, 0.f, 0.f};
      if (ADDB) bv4 = *(const float4*)&bias[rowb];
      #pragma unroll
      for (int rr = 0; rr < 4; ++rr) {
        const float bv = ((const float*)&bv4)[rr];
        const size_t rbase = (size_t)(rowb + rr) * 192;
        #pragma unroll
        for (int n = 0; n < 4; ++n) {
          const int j = colL0 + n * 16 + lr;
          Cw[rbase + j] = f2bf(acc[m][n][rr] + bv);
        }
      }
    }
    return;
  }

  #pragma unroll
  for (int n = 0; n < 4; ++n) {
    const int ccol = colL0 + n * 16 + lr;
    const float bv = ADDB ? bias[ccol] : 0.f;
    #pragma unroll
    for (int m = 0; m < 4; ++m) {
      #pragma unroll
      for (int r = 0; r < 4; ++r) {
        const int crow = row0 + m * 16 + kg * 4 + r;
        float v = acc[m][n][r] + bv;
        if (RELU) v = fmaxf(v, 0.f);
        if (OUTF32)
          ((float*)Cv)[(size_t)crow * ldC + colOff + ccol] = v;
        else
          ((unsigned short*)Cv)[(size_t)crow * ldC + colOff + ccol] = f2bf(v);
      }
    }
  }
}

// ---------------- MFMA sliding-window attention ---------------------------
// Block = (b, n, head-group of 4). Wave w handles head hg*4+w independently.
// qk: (36864, 1024) bf16 [Q | K].  vt: [b1][h][64][192] bf16.
// ctx out: row stride ldc, column offset colOff. S^T = mfma(K,Q): col=q,row=k.
__global__ __launch_bounds__(256)
void attn_mfma(const unsigned short* __restrict__ qk,
               const unsigned short* __restrict__ vt,
               unsigned short* __restrict__ ctx, int hbranch, int ldc, int colOff)
{
  __shared__ unsigned short P_lds[4][32 * 104];
  __shared__ float rinv[4][32];

  const int t = threadIdx.x;
  const int w = t >> 6, l = t & 63;
  const int lr = l & 15, kg = l >> 4;
  const int bid = blockIdx.x;
  const int hg = bid & 1;
  const int n = (bid >> 1) % 6;
  const int b = bid / 12;
  const int h = hg * 4 + w;
  const int kabase = (n - 1) * 32;

  bf16x8 qf[2][2];
  #pragma unroll
  for (int ct = 0; ct < 2; ++ct)
    #pragma unroll
    for (int ks = 0; ks < 2; ++ks)
      qf[ct][ks] = *(const bf16x8*)&qk[(size_t)(b * 192 + n * 32 + ct * 16 + lr) * 1024
                                       + h * 64 + ks * 32 + kg * 8];

  const f32x4 z4 = {0.f, 0.f, 0.f, 0.f};
  f32x4 sacc[6][2];
  #pragma unroll
  for (int mt = 0; mt < 6; ++mt) { sacc[mt][0] = z4; sacc[mt][1] = z4; }

  #pragma unroll
  for (int mt = 0; mt < 6; ++mt) {
    int ka = kabase + mt * 16 + lr;
    ka = ka < 0 ? 0 : (ka > 191 ? 191 : ka);
    const size_t row = hbranch ? (size_t)ka * 192 + b : (size_t)b * 192 + ka;
    #pragma unroll
    for (int ks = 0; ks < 2; ++ks) {
      bf16x8 kf = *(const bf16x8*)&qk[row * 1024 + 512 + h * 64 + ks * 32 + kg * 8];
      #pragma unroll
      for (int ct = 0; ct < 2; ++ct)
        sacc[mt][ct] = __builtin_amdgcn_mfma_f32_16x16x32_bf16(kf, qf[ct][ks],
                                                               sacc[mt][ct], 0, 0, 0);
    }
  }

  bf16x8 vf[4][3];
  #pragma unroll
  for (int dt = 0; dt < 4; ++dt)
    #pragma unroll
    for (int t2 = 0; t2 < 3; ++t2) {
      int ka0 = kabase + t2 * 32 + kg * 8;
      if (ka0 < 0 || ka0 > 184) ka0 = 0;
      vf[dt][t2] = *(const bf16x8*)&vt[((size_t)(b * 8 + h) * 64 + dt * 16 + lr) * 192 + ka0];
    }

  unsigned short* Pw = &P_lds[w][0];
  #pragma unroll
  for (int ct = 0; ct < 2; ++ct) {
    const int q = ct * 16 + lr;
    float mx = -1e30f;
    #pragma unroll
    for (int mt = 0; mt < 6; ++mt)
      #pragma unroll
      for (int rr = 0; rr < 4; ++rr) {
        const int kk = mt * 16 + kg * 4 + rr;
        const int ka = kabase + kk;
        const bool valid = (kk >= q) && (kk <= q + 64) && (ka >= 0) && (ka < 192);
        const float s = valid ? sacc[mt][ct][rr] : -1e30f;
        sacc[mt][ct][rr] = s;
        mx = fmaxf(mx, s);
      }
    mx = fmaxf(mx, __shfl_xor(mx, 16));
    mx = fmaxf(mx, __shfl_xor(mx, 32));
    float sum = 0.f;
    #pragma unroll
    for (int mt = 0; mt < 6; ++mt) {
      bf16x4 pk;
      #pragma unroll
      for (int rr = 0; rr < 4; ++rr) {
        const float e = exp2f((sacc[mt][ct][rr] - mx) * 0.1803368801111137f);
        sum += e;
        pk[rr] = (__bf16)e;
      }
      *(bf16x4*)&Pw[q * 104 + mt * 16 + kg * 4] = pk;
    }
    sum += __shfl_xor(sum, 16);
    sum += __shfl_xor(sum, 32);
    if (kg == 0) rinv[w][q] = 1.0f / sum;
  }

  f32x4 oacc[2][4];
  #pragma unroll
  for (int mq = 0; mq < 2; ++mq)
    #pragma unroll
    for (int dt = 0; dt < 4; ++dt) oacc[mq][dt] = z4;

  #pragma unroll
  for (int t2 = 0; t2 < 3; ++t2)
    #pragma unroll
    for (int mq = 0; mq < 2; ++mq) {
      bf16x8 pa = *(const bf16x8*)&Pw[(mq * 16 + lr) * 104 + t2 * 32 + kg * 8];
      #pragma unroll
      for (int dt = 0; dt < 4; ++dt)
        oacc[mq][dt] = __builtin_amdgcn_mfma_f32_16x16x32_bf16(pa, vf[dt][t2],
                                                               oacc[mq][dt], 0, 0, 0);
    }

  #pragma unroll
  for (int mq = 0; mq < 2; ++mq)
    #pragma unroll
    for (int rr = 0; rr < 4; ++rr) {
      const int q = mq * 16 + kg * 4 + rr;
      const float rv = rinv[w][q];
      const size_t row = (size_t)(b * 192 + n * 32 + q) * ldc + colOff + h * 64;
      #pragma unroll
      for (int dt = 0; dt < 4; ++dt)
        ctx[row + dt * 16 + lr] = f2bf(oacc[mq][dt][rr] * rv);
    }
}

// ---------------- launch ----------------
extern "C" void kernel_launch(void* const* d_in, const int* in_sizes, int n_in,
                              void* d_out, int out_size, void* d_ws, size_t ws_size,
                              hipStream_t stream) {
  const float* x       = (const float*)d_in[0];
  const float* h_in_w  = (const float*)d_in[1];
  const float* h_in_b  = (const float*)d_in[2];
  const float* h_out_w = (const float*)d_in[3];
  const float* h_out_b = (const float*)d_in[4];
  const float* v_in_w  = (const float*)d_in[5];
  const float* v_in_b  = (const float*)d_in[6];
  const float* v_out_w = (const float*)d_in[7];
  const float* v_out_b = (const float*)d_in[8];
  const float* w1      = (const float*)d_in[9];
  const float* b1      = (const float*)d_in[10];
  const float* w2      = (const float*)d_in[11];
  const float* b2      = (const float*)d_in[12];

  // workspace layout (bytes) — total: 232,259,584
  const size_t XB   = 0;                 // xb 37,748,736 (G+bf alias after QK-v)
  const size_t WVB  = 37748736;
  const size_t WHB  = 39321600;
  const size_t WHOT = 40894464;
  const size_t WVOT = 41418752;
  const size_t W1B  = 41943040;
  const size_t W2B  = 42991616;
  const size_t CTX2 = 43515904;          // 75,497,472 (36864 x 1024 bf16)
  const size_t QKO  = 119013376;         // 75,497,472 (xt, hid alias here)
  const size_t VTO  = 194510848;         // 37,748,736
  const size_t NEED = 232259584;
  if (ws_size < NEED) return;

  char* ws = (char*)d_ws;
  unsigned short* xb   = (unsigned short*)(ws + XB);
  unsigned short* wvb  = (unsigned short*)(ws + WVB);
  unsigned short* whb  = (unsigned short*)(ws + WHB);
  unsigned short* whoT = (unsigned short*)(ws + WHOT);
  unsigned short* wvoT = (unsigned short*)(ws + WVOT);
  unsigned short* w1b  = (unsigned short*)(ws + W1B);
  unsigned short* w2b  = (unsigned short*)(ws + W2B);
  unsigned short* ctx2 = (unsigned short*)(ws + CTX2);
  unsigned short* qko  = (unsigned short*)(ws + QKO);
  unsigned short* vto  = (unsigned short*)(ws + VTO);
  unsigned short* xt   = (unsigned short*)(ws + QKO);  // alias: consumed before QK-h
  unsigned short* hid  = (unsigned short*)(ws + QKO);  // alias: after attn-v
  unsigned short* G    = (unsigned short*)(ws + XB);   // alias: after QK-v (1 MB)
  float*          bfz  = (float*)(ws + XB + 1048576);  // fused bias (2 KB)

  // 1. converts (single kernel)
  cvt_all<<<21248, 256, 0, stream>>>(x, v_in_w, h_in_w, w1, w2, h_out_w, v_out_w,
                                     xb, xt, wvb, whb, w1b, w2b, whoT, wvoT);
  // 2-4. h branch (VT-h consumes xt before QK-h overwrites the alias)
  gemm_bt<0,0,1,1><<<192 * 8, 256, 0, stream>>>(whb + 1024 * 512, xt, vto, h_in_b + 1024,
                                                512, 192, 512, 512, 512, 192, 0);
  gemm_bt<0,0,0,1><<<288 * 8, 256, 0, stream>>>(xb, whb, qko, h_in_b,
                                                36864, 1024, 512, 512, 512, 1024, 0);
  attn_mfma<<<192 * 6 * 2, 256, 0, stream>>>(qko, vto, ctx2, 1, 1024, 0);
  // 5-7. v branch
  gemm_bt<0,0,1,1><<<192 * 8, 256, 0, stream>>>(wvb + 1024 * 512, xb, vto, v_in_b + 1024,
                                                512, 192, 512, 512, 512, 192, 0);
  gemm_bt<0,0,0,1><<<288 * 8, 256, 0, stream>>>(xb, wvb, qko, v_in_b,
                                                36864, 1024, 512, 512, 512, 1024, 0);
  attn_mfma<<<192 * 6 * 2, 256, 0, stream>>>(qko, vto, ctx2, 0, 1024, 512);
  // 8-10. fused MLP1 weight: G = [W1a.who | W1b.wvo], bias bfz
  gemm_bt<0,0,0,0><<<16, 256, 0, stream>>>(w1b, whoT, G, bfz,
                                           512, 512, 512, 1024, 512, 1024, 0);
  gemm_bt<0,0,0,0><<<16, 256, 0, stream>>>(w1b + 512, wvoT, G, bfz,
                                           512, 512, 512, 1024, 512, 1024, 512);
  fuse_bias<<<32, 256, 0, stream>>>(b1, h_out_b, v_out_b, w1, bfz);
  // 11. hid = relu(ctx2 . G^T + bfz)   (out-projections folded in)
  gemm_bt<0,1,0,1><<<288 * 4, 256, 0, stream>>>(ctx2, G, hid, bfz,
                                                36864, 512, 1024, 1024, 1024, 512, 0);
  // 12. out = hid . w2^T + b2  (fp32)
  gemm_bt<1,0,0,1><<<288 * 4, 256, 0, stream>>>(hid, w2b, d_out, b2,
                                                36864, 512, 512, 512, 512, 512, 0);
}